// Round 4
// baseline (1174.307 us; speedup 1.0000x reference)
//
#include <hip/hip_runtime.h>
#include <hip/hip_fp16.h>

#define N_NODES 50000
#define DIM 128
#define NE 800000
#define MAXD 48
#define CAP 64
#define NGRP (N_NODES/16)

typedef _Float16 f16x8 __attribute__((ext_vector_type(8)));
typedef float f32x4 __attribute__((ext_vector_type(4)));

__device__ __forceinline__ float sigmf(float x){
  return __builtin_amdgcn_rcpf(1.f + __builtin_amdgcn_exp2f(-1.4426950408889634f * x));
}
__device__ __forceinline__ float tanh_fast(float x){
  float e = __builtin_amdgcn_exp2f(2.8853900817779268f * x); // e^(2x)
  return 1.f - 2.f * __builtin_amdgcn_rcpf(e + 1.f);
}
__device__ __forceinline__ unsigned short f2h(float f){
  union{_Float16 h; unsigned short s;} c; c.h=(_Float16)f; return c.s;
}
__device__ __forceinline__ float h2f(unsigned short u){
  union{unsigned short s; _Float16 h;} c; c.s=u; return (float)c.h;
}

__global__ void kZero(int* p, int n){
  int i = blockIdx.x*blockDim.x + threadIdx.x;
  if(i<n) p[i]=0;
}

__global__ void kColStats(const float* __restrict__ feat, float* __restrict__ P, float* __restrict__ P2){
  int d = threadIdx.x; int b = blockIdx.x;
  float s=0.f, s2=0.f;
  for(int r=b; r<N_NODES; r+=256){ float v = feat[r*DIM+d]; s+=v; s2+=v*v; }
  P[b*DIM+d]=s; P2[b*DIM+d]=s2;
}

__global__ void kFinStats(const float* __restrict__ P, const float* __restrict__ P2,
                          const float* __restrict__ gamma, const float* __restrict__ beta,
                          float* __restrict__ scale, float* __restrict__ shift){
  int d = threadIdx.x;
  float s=0.f, s2=0.f;
  for(int b=0;b<256;b++){ s+=P[b*DIM+d]; s2+=P2[b*DIM+d]; }
  float mu = s/(float)N_NODES;
  float var = s2/(float)N_NODES - mu*mu;
  float rs = rsqrtf(var + 1e-5f);
  float sc = rs*gamma[d];
  scale[d]=sc; shift[d]=beta[d]-mu*sc;
}

__global__ void kEdges(const int* __restrict__ dst, int* __restrict__ cnt, int* __restrict__ elist){
  for(int e = blockIdx.x*blockDim.x+threadIdx.x; e < NE; e += gridDim.x*blockDim.x){
    int d = dst[e];
    int slot = atomicAdd(&cnt[d],1);
    if(slot < CAP) elist[d*CAP+slot] = e;
  }
}

__global__ void kSortSrc(const int* __restrict__ src, const int* __restrict__ cnt,
                         int* __restrict__ elist, int* __restrict__ len){
  int n = blockIdx.x*blockDim.x+threadIdx.x; if(n>=N_NODES) return;
  int m = cnt[n]; if(m>CAP) m=CAP;
  int* el = elist + n*CAP;
  for(int i=1;i<m;i++){ int v=el[i]; int j=i-1; while(j>=0 && el[j]>v){ el[j+1]=el[j]; j--; } el[j+1]=v; }
  int L = m; if(L>MAXD) L=MAXD;
  len[n]=L;
  for(int t=0;t<L;t++) el[t] = src[el[t]];
}

__global__ void kHist(const int* __restrict__ len, int* __restrict__ hist){
  int n=blockIdx.x*blockDim.x+threadIdx.x;
  if(n<N_NODES) atomicAdd(&hist[len[n]],1);
}
__global__ void kScan(const int* __restrict__ hist, int* __restrict__ offs){
  if(threadIdx.x==0){ int s=0; for(int i=0;i<=MAXD;i++){ offs[i]=s; s+=hist[i]; } }
}
__global__ void kScatter(const int* __restrict__ len, int* __restrict__ offs, int* __restrict__ perm){
  int n=blockIdx.x*blockDim.x+threadIdx.x;
  if(n<N_NODES){ int r=atomicAdd((int*)&offs[len[n]],1); perm[r]=n; }
}

// MFMA GEMM: GIh[n][0:384] = f16(x@W_ih^T + b_ih), out[n][0:128] = x@W_self^T.
// BN folded into weights: W'[j][d]=scale[d]*W[j][d], b'[j]=sum_d shift[d]*W[j][d] (+bih).
// W' f16 in 128KB swizzled LDS; each wave processes whole 16-node groups independently.
__global__ __launch_bounds__(256,1) void kXG2(const float* __restrict__ feat,
    const float* __restrict__ scale, const float* __restrict__ shift,
    const float* __restrict__ Wih, const float* __restrict__ bih,
    const float* __restrict__ Wself,
    unsigned short* __restrict__ GIh, float* __restrict__ out)
{
  __shared__ unsigned short Wl[512*128]; // 128KB, rows 256B, 16B blocks XOR-swizzled by row&7
  __shared__ float bL[512];
  const int tid=threadIdx.x, w=tid>>6, l=tid&63, g=l&15, q=l>>4;
  for(int i=tid;i<8192;i+=256){
    int j=i>>4, blk=i&15, d0=blk*8;
    const float* Wsrc=(j<384)? &Wih[(size_t)j*DIM] : &Wself[(size_t)(j-384)*DIM];
    float partial=0.f; unsigned u[4];
    #pragma unroll
    for(int e2=0;e2<4;e2++){
      float w0=Wsrc[d0+2*e2], w1=Wsrc[d0+2*e2+1];
      partial += shift[d0+2*e2]*w0 + shift[d0+2*e2+1]*w1;
      u[e2]=(unsigned)f2h(w0*scale[d0+2*e2]) | ((unsigned)f2h(w1*scale[d0+2*e2+1])<<16);
    }
    partial+=__shfl_xor(partial,1); partial+=__shfl_xor(partial,2);
    partial+=__shfl_xor(partial,4); partial+=__shfl_xor(partial,8);
    if((i&15)==0) bL[j]=partial+((j<384)? bih[j]:0.f);
    char* dp=(char*)Wl + j*256 + ((blk^(j&7))<<4);
    *(uint4*)dp=make_uint4(u[0],u[1],u[2],u[3]);
  }
  __syncthreads();
  for(int grp=blockIdx.x*4+w; grp<NGRP; grp+=gridDim.x*4){
    const int n=grp*16+g;
    const float* fp=feat+(size_t)n*DIM;
    f16x8 Bf[4];
    #pragma unroll
    for(int ks=0;ks<4;ks++){
      float4 a=*(const float4*)&fp[32*ks+8*q];
      float4 b=*(const float4*)&fp[32*ks+8*q+4];
      f16x8 v; v[0]=(_Float16)a.x; v[1]=(_Float16)a.y; v[2]=(_Float16)a.z; v[3]=(_Float16)a.w;
      v[4]=(_Float16)b.x; v[5]=(_Float16)b.y; v[6]=(_Float16)b.z; v[7]=(_Float16)b.w;
      Bf[ks]=v;
    }
    for(int tile=0;tile<32;tile++){
      const int jbase=tile*16;
      f32x4 a={0.f,0.f,0.f,0.f};
      #pragma unroll
      for(int ks=0;ks<4;ks++){
        const char* ap=(const char*)Wl + (jbase+g)*256 + (((4*ks+q)^(g&7))<<4);
        a=__builtin_amdgcn_mfma_f32_16x16x32_f16(*(const f16x8*)ap,Bf[ks],a,0,0,0);
      }
      float4 bb=*(const float4*)&bL[jbase+4*q];
      if(tile<24){
        unsigned lo=(unsigned)f2h(a[0]+bb.x)|((unsigned)f2h(a[1]+bb.y)<<16);
        unsigned hi=(unsigned)f2h(a[2]+bb.z)|((unsigned)f2h(a[3]+bb.w)<<16);
        *(uint2*)&GIh[(size_t)n*384+jbase+4*q]=make_uint2(lo,hi);
      } else {
        float4 o; o.x=a[0]+bb.x; o.y=a[1]+bb.y; o.z=a[2]+bb.z; o.w=a[3]+bb.w;
        *(float4*)&out[(size_t)n*DIM + (jbase-384)+4*q]=o;
      }
    }
  }
}

// MFMA-batched GRU: one 4-wave block per group of 16 degree-sorted nodes.
__global__ __launch_bounds__(256,3) void kGruM(const unsigned short* __restrict__ GIh,
    const int* __restrict__ elist, const int* __restrict__ len, const int* __restrict__ perm,
    const float* __restrict__ Whh, const float* __restrict__ bhh,
    const float* __restrict__ Wneigh, float* __restrict__ out)
{
  __shared__ unsigned short hbuf[2][2][16][128]; // [buf][plane hi/lo][g][d], XOR-swizzled rows, 16KB
  __shared__ unsigned short WnL[128*128];        // W_neigh f16, 256B rows, 16B blocks XOR-swizzled, 32KB
  const int tid=threadIdx.x, w=tid>>6, l=tid&63, g=l&15, q=l>>4;

  for(int i=tid;i<2048;i+=256){
    int j=i>>4, blk=i&15;
    const float* p=&Wneigh[(size_t)j*DIM + blk*8];
    unsigned u0=(unsigned)f2h(p[0])|((unsigned)f2h(p[1])<<16);
    unsigned u1=(unsigned)f2h(p[2])|((unsigned)f2h(p[3])<<16);
    unsigned u2=(unsigned)f2h(p[4])|((unsigned)f2h(p[5])<<16);
    unsigned u3=(unsigned)f2h(p[6])|((unsigned)f2h(p[7])<<16);
    char* dp=(char*)WnL + j*256 + ((blk^(j&7))<<4);
    *(uint4*)dp=make_uint4(u0,u1,u2,u3);
  }
  // W_hh A-fragments: A[m][k]: m=l&15 (j-row), k=8*(l>>4)+e (d)
  f16x8 Wf[6][4];
  #pragma unroll
  for(int fi=0;fi<6;fi++){
    const int gt=fi>>1, tt=fi&1;
    const int j=gt*128+32*w+16*tt+g;
    #pragma unroll
    for(int ks=0;ks<4;ks++){
      const float* p=&Whh[j*DIM+32*ks+8*q];
      f16x8 v;
      #pragma unroll
      for(int e=0;e<8;e++) v[e]=(_Float16)p[e];
      Wf[fi][ks]=v;
    }
  }
  float bh[6][4];
  #pragma unroll
  for(int fi=0;fi<6;fi++){ const int gt=fi>>1, tt=fi&1;
    #pragma unroll
    for(int r=0;r<4;r++) bh[fi][r]=bhh[gt*128+32*w+16*tt+4*q+r];
  }

  for(int grp=blockIdx.x; grp<NGRP; grp+=gridDim.x){
    __syncthreads();                       // prev epilogue readers done
    for(int i=tid;i<1024;i+=256) ((uint4*)hbuf)[i]=make_uint4(0,0,0,0);
    const int n_g=perm[grp*16+g];
    const int Lg=len[n_g];
    int T=Lg;
    T=max(T,__shfl_xor(T,1)); T=max(T,__shfl_xor(T,2));
    T=max(T,__shfl_xor(T,4)); T=max(T,__shfl_xor(T,8));
    __syncthreads();
    const int* el=elist+(size_t)n_g*CAP;
    int sNext=0; uint2 gi[6];
    if(T>0){
      int s0=(Lg>0)?el[0]:0;
      sNext=(Lg>1)?el[1]:s0;
      const unsigned short* gp=GIh+(size_t)s0*384;
      #pragma unroll
      for(int fi=0;fi<6;fi++){ const int gt=fi>>1, tt=fi&1;
        gi[fi]=*(const uint2*)&gp[gt*128+32*w+16*tt+4*q]; }
    }
    float h[2][4]={{0.f,0.f,0.f,0.f},{0.f,0.f,0.f,0.f}};
    for(int t=0;t<T;t++){
      const int cb=t&1, cbn=cb^1;
      f16x8 Bf[4][2];
      #pragma unroll
      for(int ks=0;ks<4;ks++){
        #pragma unroll
        for(int p=0;p<2;p++){
          const char* bp=(const char*)hbuf + ((cb*2+p)*16+g)*256 + (((4*ks+q)^(g&7))*16);
          Bf[ks][p]=*(const f16x8*)bp;
        }
      }
      f32x4 acc[6];
      #pragma unroll
      for(int fi=0;fi<6;fi++){
        f32x4 a={0.f,0.f,0.f,0.f};
        #pragma unroll
        for(int ks=0;ks<4;ks++) a=__builtin_amdgcn_mfma_f32_16x16x32_f16(Wf[fi][ks],Bf[ks][1],a,0,0,0);
        #pragma unroll
        for(int ks=0;ks<4;ks++) a=__builtin_amdgcn_mfma_f32_16x16x32_f16(Wf[fi][ks],Bf[ks][0],a,0,0,0);
        acc[fi]=a;
      }
      float giv[6][4];
      #pragma unroll
      for(int fi=0;fi<6;fi++){
        giv[fi][0]=h2f((unsigned short)(gi[fi].x&0xffffu));
        giv[fi][1]=h2f((unsigned short)(gi[fi].x>>16));
        giv[fi][2]=h2f((unsigned short)(gi[fi].y&0xffffu));
        giv[fi][3]=h2f((unsigned short)(gi[fi].y>>16));
      }
      if(t+1<T){
        const unsigned short* gp=GIh+(size_t)sNext*384;
        #pragma unroll
        for(int fi=0;fi<6;fi++){ const int gt=fi>>1, tt=fi&1;
          gi[fi]=*(const uint2*)&gp[gt*128+32*w+16*tt+4*q]; }
      }
      int ii=t+2; ii=(ii>Lg-1)?(Lg-1):ii; ii=(ii<0)?0:ii;
      const int sN2=(Lg>0)?el[ii]:0;
      const bool act=(t<Lg);
      #pragma unroll
      for(int tt=0;tt<2;tt++){
        #pragma unroll
        for(int r=0;r<4;r++){
          float rr=sigmf(giv[tt][r]+acc[tt][r]+bh[tt][r]);
          float zz=sigmf(giv[2+tt][r]+acc[2+tt][r]+bh[2+tt][r]);
          float nn=tanh_fast(giv[4+tt][r]+rr*(acc[4+tt][r]+bh[4+tt][r]));
          float hn=(1.f-zz)*nn+zz*h[tt][r];
          h[tt][r]=act?hn:h[tt][r];
        }
      }
      #pragma unroll
      for(int tt=0;tt<2;tt++){
        unsigned short a0=f2h(h[tt][0]),a1=f2h(h[tt][1]),a2=f2h(h[tt][2]),a3=f2h(h[tt][3]);
        unsigned short b0=f2h(h[tt][0]-h2f(a0)),b1=f2h(h[tt][1]-h2f(a1));
        unsigned short b2=f2h(h[tt][2]-h2f(a2)),b3=f2h(h[tt][3]-h2f(a3));
        const int blk=((4*w+2*tt+(q>>1))^(g&7));
        const int sub=8*(q&1);
        char* p0=(char*)hbuf + ((cbn*2+0)*16+g)*256 + blk*16 + sub;
        char* p1=(char*)hbuf + ((cbn*2+1)*16+g)*256 + blk*16 + sub;
        *(uint2*)p0=make_uint2((unsigned)a0|((unsigned)a1<<16),(unsigned)a2|((unsigned)a3<<16));
        *(uint2*)p1=make_uint2((unsigned)b0|((unsigned)b1<<16),(unsigned)b2|((unsigned)b3<<16));
      }
      __syncthreads();
      sNext=sN2;
    }
    // epilogue: out += W_neigh · h_final (hi+lo planes)
    const int fb=T&1;
    #pragma unroll
    for(int tt=0;tt<2;tt++){
      f32x4 a={0.f,0.f,0.f,0.f};
      #pragma unroll
      for(int ks=0;ks<4;ks++){
        const char* ap=(const char*)WnL + (32*w+16*tt+g)*256 + (((4*ks+q)^(g&7))<<4);
        const f16x8 Af=*(const f16x8*)ap;
        const char* bl=(const char*)hbuf + ((fb*2+1)*16+g)*256 + (((4*ks+q)^(g&7))*16);
        const char* bhp=(const char*)hbuf + ((fb*2+0)*16+g)*256 + (((4*ks+q)^(g&7))*16);
        a=__builtin_amdgcn_mfma_f32_16x16x32_f16(Af,*(const f16x8*)bl,a,0,0,0);
        a=__builtin_amdgcn_mfma_f32_16x16x32_f16(Af,*(const f16x8*)bhp,a,0,0,0);
      }
      float* po=&out[(size_t)n_g*DIM + 32*w+16*tt+4*q];
      float4 cur=*(float4*)po;
      cur.x+=a[0]; cur.y+=a[1]; cur.z+=a[2]; cur.w+=a[3];
      *(float4*)po=cur;
    }
  }
}

extern "C" void kernel_launch(void* const* d_in, const int* in_sizes, int n_in,
                              void* d_out, int out_size, void* d_ws, size_t ws_size,
                              hipStream_t stream){
  const float* feat  = (const float*)d_in[0];
  const int*   src   = (const int*)d_in[1];
  const int*   dst   = (const int*)d_in[2];
  const float* gamma = (const float*)d_in[3];
  const float* beta  = (const float*)d_in[4];
  const float* Wih   = (const float*)d_in[5];
  const float* Whh   = (const float*)d_in[6];
  const float* bih   = (const float*)d_in[7];
  const float* bhh   = (const float*)d_in[8];
  const float* Wself = (const float*)d_in[9];
  const float* Wneigh= (const float*)d_in[10];
  float* out = (float*)d_out;

  char* ws = (char*)d_ws;
  size_t off = 0;
  auto alloc = [&](size_t bytes)->void*{ void* p = ws+off; off += (bytes+511)&~(size_t)511; return p; };
  float* P     = (float*)alloc(256*128*4);
  float* P2    = (float*)alloc(256*128*4);
  float* scale = (float*)alloc(512);
  float* shift = (float*)alloc(512);
  int*   cnt   = (int*)alloc((size_t)N_NODES*4);
  int*   lenp  = (int*)alloc((size_t)N_NODES*4);
  int*   hist  = (int*)alloc((MAXD+1)*4);
  int*   offs  = (int*)alloc((MAXD+1)*4);
  int*   perm  = (int*)alloc((size_t)N_NODES*4);
  int*   elist = (int*)alloc((size_t)N_NODES*CAP*4);
  unsigned short* GIh = (unsigned short*)alloc((size_t)N_NODES*384*2);

  kZero<<<(N_NODES+255)/256, 256, 0, stream>>>(cnt, N_NODES);
  kZero<<<1, 64, 0, stream>>>(hist, MAXD+1);
  kColStats<<<256,128,0,stream>>>(feat, P, P2);
  kFinStats<<<1,128,0,stream>>>(P,P2,gamma,beta,scale,shift);
  kEdges<<<1024,256,0,stream>>>(dst, cnt, elist);
  kSortSrc<<<(N_NODES+255)/256,256,0,stream>>>(src, cnt, elist, lenp);
  kHist<<<(N_NODES+255)/256,256,0,stream>>>(lenp, hist);
  kScan<<<1,64,0,stream>>>(hist, offs);
  kScatter<<<(N_NODES+255)/256,256,0,stream>>>(lenp, offs, perm);
  kXG2<<<256,256,0,stream>>>(feat, scale, shift, Wih, bih, Wself, GIh, out);
  kGruM<<<768,256,0,stream>>>(GIh, elist, lenp, perm, Whh, bhh, Wneigh, out);
}

// Round 5
// 880.588 us; speedup vs baseline: 1.3335x; 1.3335x over previous
//
#include <hip/hip_runtime.h>
#include <hip/hip_fp16.h>

#define N_NODES 50000
#define DIM 128
#define NE 800000
#define MAXD 48
#define CAP 64
#define NGRP (N_NODES/16)
#define NPAIR ((NGRP+1)/2)

typedef _Float16 f16x8 __attribute__((ext_vector_type(8)));
typedef float f32x4 __attribute__((ext_vector_type(4)));

__device__ __forceinline__ float sigmf(float x){
  return __builtin_amdgcn_rcpf(1.f + __builtin_amdgcn_exp2f(-1.4426950408889634f * x));
}
__device__ __forceinline__ float tanh_fast(float x){
  float e = __builtin_amdgcn_exp2f(2.8853900817779268f * x);
  return 1.f - 2.f * __builtin_amdgcn_rcpf(e + 1.f);
}
__device__ __forceinline__ unsigned short f2h(float f){
  union{_Float16 h; unsigned short s;} c; c.h=(_Float16)f; return c.s;
}
__device__ __forceinline__ float h2f(unsigned short u){
  union{unsigned short s; _Float16 h;} c; c.s=u; return (float)c.h;
}

__global__ void kZero2(int* a, int na, int* b, int nb){
  int i = blockIdx.x*blockDim.x + threadIdx.x;
  if(i<na) a[i]=0;
  if(i<nb) b[i]=0;
}

__global__ void kColStats(const float* __restrict__ feat, float* __restrict__ P, float* __restrict__ P2){
  int d = threadIdx.x; int b = blockIdx.x;
  float s=0.f, s2=0.f;
  for(int r=b; r<N_NODES; r+=256){ float v = feat[r*DIM+d]; s+=v; s2+=v*v; }
  P[b*DIM+d]=s; P2[b*DIM+d]=s2;
}

__global__ void kFinStats(const float* __restrict__ P, const float* __restrict__ P2,
                          const float* __restrict__ gamma, const float* __restrict__ beta,
                          float* __restrict__ scale, float* __restrict__ shift){
  int d = threadIdx.x;
  float s=0.f, s2=0.f;
  for(int b=0;b<256;b++){ s+=P[b*DIM+d]; s2+=P2[b*DIM+d]; }
  float mu = s/(float)N_NODES;
  float var = s2/(float)N_NODES - mu*mu;
  float rs = rsqrtf(var + 1e-5f);
  float sc = rs*gamma[d];
  scale[d]=sc; shift[d]=beta[d]-mu*sc;
}

__global__ void kEdges(const int* __restrict__ dst, int* __restrict__ cnt, int* __restrict__ elist){
  for(int e = blockIdx.x*blockDim.x+threadIdx.x; e < NE; e += gridDim.x*blockDim.x){
    int d = dst[e];
    int slot = atomicAdd(&cnt[d],1);
    if(slot < CAP) elist[(size_t)d*CAP+slot] = e;
  }
}

// One wave per node: 64-lane bitonic sort of edge ids, then resolve to src; merges hist.
__global__ __launch_bounds__(256) void kSortW(const int* __restrict__ src, const int* __restrict__ cnt,
    int* __restrict__ elist, int* __restrict__ len, int* __restrict__ hist){
  int n = blockIdx.x*4 + (threadIdx.x>>6);
  if(n>=N_NODES) return;
  int l = threadIdx.x&63;
  int m = cnt[n]; m = m>CAP? CAP : m;
  int* el = elist + (size_t)n*CAP;
  int v = (l<m)? el[l] : 0x7fffffff;
  #pragma unroll
  for(int k=2;k<=64;k<<=1){
    #pragma unroll
    for(int j=k>>1;j>0;j>>=1){
      int u = __shfl_xor(v,j);
      bool up = ((l&k)==0);
      bool lower = ((l&j)==0);
      int mn = v<u? v:u, mx = v<u? u:v;
      v = (lower==up)? mn : mx;
    }
  }
  int L = m<MAXD? m : MAXD;
  if(l==0){ len[n]=L; atomicAdd(&hist[L],1); }
  if(l<L) el[l] = src[v];
}

__global__ void kScan(const int* __restrict__ hist, int* __restrict__ offs){
  if(threadIdx.x==0){ int s=0; for(int i=0;i<=MAXD;i++){ offs[i]=s; s+=hist[i]; } }
}
__global__ void kScatter(const int* __restrict__ len, int* __restrict__ offs, int* __restrict__ perm){
  int n=blockIdx.x*blockDim.x+threadIdx.x;
  if(n<N_NODES){ int r=atomicAdd((int*)&offs[len[n]],1); perm[r]=n; }
}

// MFMA GEMM: GIh[n][j] = f16(x@Wih^T + bih + (j<256? bhh:0)), out[n] = x@Wself^T.
// BN folded into weights.
__global__ __launch_bounds__(256,1) void kXG2(const float* __restrict__ feat,
    const float* __restrict__ scale, const float* __restrict__ shift,
    const float* __restrict__ Wih, const float* __restrict__ bih, const float* __restrict__ bhh,
    const float* __restrict__ Wself,
    unsigned short* __restrict__ GIh, float* __restrict__ out)
{
  __shared__ unsigned short Wl[512*128];
  __shared__ float bL[512];
  const int tid=threadIdx.x, w=tid>>6, l=tid&63, g=l&15, q=l>>4;
  for(int i=tid;i<8192;i+=256){
    int j=i>>4, blk=i&15, d0=blk*8;
    const float* Wsrc=(j<384)? &Wih[(size_t)j*DIM] : &Wself[(size_t)(j-384)*DIM];
    float partial=0.f; unsigned u[4];
    #pragma unroll
    for(int e2=0;e2<4;e2++){
      float w0=Wsrc[d0+2*e2], w1=Wsrc[d0+2*e2+1];
      partial += shift[d0+2*e2]*w0 + shift[d0+2*e2+1]*w1;
      u[e2]=(unsigned)f2h(w0*scale[d0+2*e2]) | ((unsigned)f2h(w1*scale[d0+2*e2+1])<<16);
    }
    partial+=__shfl_xor(partial,1); partial+=__shfl_xor(partial,2);
    partial+=__shfl_xor(partial,4); partial+=__shfl_xor(partial,8);
    if((i&15)==0){
      float bb=partial;
      if(j<384) bb+=bih[j];
      if(j<256) bb+=bhh[j];
      bL[j]=bb;
    }
    char* dp=(char*)Wl + j*256 + ((blk^(j&7))<<4);
    *(uint4*)dp=make_uint4(u[0],u[1],u[2],u[3]);
  }
  __syncthreads();
  for(int grp=blockIdx.x*4+w; grp<NGRP; grp+=gridDim.x*4){
    const int n=grp*16+g;
    const float* fp=feat+(size_t)n*DIM;
    f16x8 Bf[4];
    #pragma unroll
    for(int ks=0;ks<4;ks++){
      float4 a=*(const float4*)&fp[32*ks+8*q];
      float4 b=*(const float4*)&fp[32*ks+8*q+4];
      f16x8 v; v[0]=(_Float16)a.x; v[1]=(_Float16)a.y; v[2]=(_Float16)a.z; v[3]=(_Float16)a.w;
      v[4]=(_Float16)b.x; v[5]=(_Float16)b.y; v[6]=(_Float16)b.z; v[7]=(_Float16)b.w;
      Bf[ks]=v;
    }
    for(int tile=0;tile<32;tile++){
      const int jbase=tile*16;
      f32x4 a={0.f,0.f,0.f,0.f};
      #pragma unroll
      for(int ks=0;ks<4;ks++){
        const char* ap=(const char*)Wl + (jbase+g)*256 + (((4*ks+q)^(g&7))<<4);
        a=__builtin_amdgcn_mfma_f32_16x16x32_f16(*(const f16x8*)ap,Bf[ks],a,0,0,0);
      }
      float4 bb=*(const float4*)&bL[jbase+4*q];
      if(tile<24){
        unsigned lo=(unsigned)f2h(a[0]+bb.x)|((unsigned)f2h(a[1]+bb.y)<<16);
        unsigned hi=(unsigned)f2h(a[2]+bb.z)|((unsigned)f2h(a[3]+bb.w)<<16);
        *(uint2*)&GIh[(size_t)n*384+jbase+4*q]=make_uint2(lo,hi);
      } else {
        float4 o; o.x=a[0]+bb.x; o.y=a[1]+bb.y; o.z=a[2]+bb.z; o.w=a[3]+bb.w;
        *(float4*)&out[(size_t)n*DIM + (jbase-384)+4*q]=o;
      }
    }
  }
}

// MFMA GRU, two-group software pipeline per 4-wave block.
__global__ __launch_bounds__(256,2) void kGruM(const unsigned short* __restrict__ GIh,
    const int* __restrict__ elist, const int* __restrict__ len, const int* __restrict__ perm,
    const float* __restrict__ Whh, const float* __restrict__ bhh,
    const float* __restrict__ Wneigh, float* __restrict__ out)
{
  __shared__ unsigned short hbuf[2][2][2][16][128]; // [grp][buf][plane][g][d] 32KB, swizzled rows
  __shared__ unsigned short WnL[128*128];           // 32KB swizzled
  const int tid=threadIdx.x, w=tid>>6, l=tid&63, g=l&15, q=l>>4;

  for(int i=tid;i<2048;i+=256){
    int j=i>>4, blk=i&15;
    const float* p=&Wneigh[(size_t)j*DIM + blk*8];
    unsigned u0=(unsigned)f2h(p[0])|((unsigned)f2h(p[1])<<16);
    unsigned u1=(unsigned)f2h(p[2])|((unsigned)f2h(p[3])<<16);
    unsigned u2=(unsigned)f2h(p[4])|((unsigned)f2h(p[5])<<16);
    unsigned u3=(unsigned)f2h(p[6])|((unsigned)f2h(p[7])<<16);
    char* dp=(char*)WnL + j*256 + ((blk^(j&7))<<4);
    *(uint4*)dp=make_uint4(u0,u1,u2,u3);
  }
  f16x8 Wf[6][4];
  #pragma unroll
  for(int fi=0;fi<6;fi++){
    const int gt=fi>>1, tt=fi&1;
    const int j=gt*128+32*w+16*tt+g;
    #pragma unroll
    for(int ks=0;ks<4;ks++){
      const float* p=&Whh[j*DIM+32*ks+8*q];
      f16x8 v;
      #pragma unroll
      for(int e=0;e<8;e++) v[e]=(_Float16)p[e];
      Wf[fi][ks]=v;
    }
  }
  float bhn[2][4];
  #pragma unroll
  for(int tt=0;tt<2;tt++)
    #pragma unroll
    for(int r=0;r<4;r++) bhn[tt][r]=bhh[256+32*w+16*tt+4*q+r];

  for(int gp=blockIdx.x; gp<NPAIR; gp+=gridDim.x){
    __syncthreads();
    for(int i=tid;i<2048;i+=256) ((uint4*)hbuf)[i]=make_uint4(0,0,0,0);
    const int nA=perm[(2*gp)*16+g];
    const bool gvB=(2*gp+1)<NGRP;
    const int nB=gvB? perm[(2*gp+1)*16+g]:0;
    const int LA=len[nA];
    const int LB=gvB? len[nB]:0;
    int T=LA>LB?LA:LB;
    T=max(T,__shfl_xor(T,1)); T=max(T,__shfl_xor(T,2));
    T=max(T,__shfl_xor(T,4)); T=max(T,__shfl_xor(T,8));
    __syncthreads();
    if(T==0) continue;
    const int* eA=elist+(size_t)nA*CAP;
    const int* eB=elist+(size_t)nB*CAP;
    int sNA, sNB;
    uint2 giA[6], giB[6];
    {
      int s0=(LA>0)?eA[0]:0;
      sNA=(LA>1)?eA[1]:s0;
      const unsigned short* gpp=GIh+(size_t)s0*384;
      #pragma unroll
      for(int fi=0;fi<6;fi++){ const int gt=fi>>1, tt=fi&1;
        giA[fi]=*(const uint2*)&gpp[gt*128+32*w+16*tt+4*q]; }
      int s0b=(LB>0)?eB[0]:0;
      sNB=(LB>1)?eB[1]:s0b;
      const unsigned short* gpb=GIh+(size_t)s0b*384;
      #pragma unroll
      for(int fi=0;fi<6;fi++){ const int gt=fi>>1, tt=fi&1;
        giB[fi]=*(const uint2*)&gpb[gt*128+32*w+16*tt+4*q]; }
    }
    float hA[2][4]={{0.f,0.f,0.f,0.f},{0.f,0.f,0.f,0.f}};
    float hB[2][4]={{0.f,0.f,0.f,0.f},{0.f,0.f,0.f,0.f}};
    for(int t=0;t<T;t++){
      const int cb=t&1, cbn=cb^1;
      // ================= group A =================
      {
        f16x8 Bf[4][2];
        #pragma unroll
        for(int ks=0;ks<4;ks++)
          #pragma unroll
          for(int p=0;p<2;p++){
            const char* bp=(const char*)hbuf + (((0*2+cb)*2+p)*16+g)*256 + (((4*ks+q)^(g&7))<<4);
            Bf[ks][p]=*(const f16x8*)bp;
          }
        f32x4 acc[6];
        #pragma unroll
        for(int fi=0;fi<6;fi++){
          f32x4 a={0.f,0.f,0.f,0.f};
          #pragma unroll
          for(int ks=0;ks<4;ks++) a=__builtin_amdgcn_mfma_f32_16x16x32_f16(Wf[fi][ks],Bf[ks][1],a,0,0,0);
          #pragma unroll
          for(int ks=0;ks<4;ks++) a=__builtin_amdgcn_mfma_f32_16x16x32_f16(Wf[fi][ks],Bf[ks][0],a,0,0,0);
          acc[fi]=a;
        }
        float gv[6][4];
        #pragma unroll
        for(int fi=0;fi<6;fi++){
          gv[fi][0]=h2f((unsigned short)(giA[fi].x&0xffffu));
          gv[fi][1]=h2f((unsigned short)(giA[fi].x>>16));
          gv[fi][2]=h2f((unsigned short)(giA[fi].y&0xffffu));
          gv[fi][3]=h2f((unsigned short)(giA[fi].y>>16));
        }
        if(t+1<T){
          const unsigned short* gpp=GIh+(size_t)sNA*384;
          #pragma unroll
          for(int fi=0;fi<6;fi++){ const int gt=fi>>1, tt=fi&1;
            giA[fi]=*(const uint2*)&gpp[gt*128+32*w+16*tt+4*q]; }
        }
        int ii=t+2; ii=(ii>LA-1)?(LA-1):ii; ii=(ii<0)?0:ii;
        const int sA2=(LA>0)?eA[ii]:0;
        const bool act=(t<LA);
        #pragma unroll
        for(int tt=0;tt<2;tt++)
          #pragma unroll
          for(int r=0;r<4;r++){
            float rr=sigmf(gv[tt][r]+acc[tt][r]);
            float zz=sigmf(gv[2+tt][r]+acc[2+tt][r]);
            float nn=tanh_fast(gv[4+tt][r]+rr*(acc[4+tt][r]+bhn[tt][r]));
            float hn=(1.f-zz)*nn+zz*hA[tt][r];
            hA[tt][r]=act?hn:hA[tt][r];
          }
        #pragma unroll
        for(int tt=0;tt<2;tt++){
          unsigned short a0=f2h(hA[tt][0]),a1=f2h(hA[tt][1]),a2=f2h(hA[tt][2]),a3=f2h(hA[tt][3]);
          unsigned short b0=f2h(hA[tt][0]-h2f(a0)),b1=f2h(hA[tt][1]-h2f(a1));
          unsigned short b2=f2h(hA[tt][2]-h2f(a2)),b3=f2h(hA[tt][3]-h2f(a3));
          const int blk=((4*w+2*tt+(q>>1))^(g&7));
          const int sub=8*(q&1);
          char* p0=(char*)hbuf + (((0*2+cbn)*2+0)*16+g)*256 + blk*16 + sub;
          char* p1=(char*)hbuf + (((0*2+cbn)*2+1)*16+g)*256 + blk*16 + sub;
          *(uint2*)p0=make_uint2((unsigned)a0|((unsigned)a1<<16),(unsigned)a2|((unsigned)a3<<16));
          *(uint2*)p1=make_uint2((unsigned)b0|((unsigned)b1<<16),(unsigned)b2|((unsigned)b3<<16));
        }
        sNA=sA2;
      }
      // ================= group B =================
      {
        f16x8 Bf[4][2];
        #pragma unroll
        for(int ks=0;ks<4;ks++)
          #pragma unroll
          for(int p=0;p<2;p++){
            const char* bp=(const char*)hbuf + (((1*2+cb)*2+p)*16+g)*256 + (((4*ks+q)^(g&7))<<4);
            Bf[ks][p]=*(const f16x8*)bp;
          }
        f32x4 acc[6];
        #pragma unroll
        for(int fi=0;fi<6;fi++){
          f32x4 a={0.f,0.f,0.f,0.f};
          #pragma unroll
          for(int ks=0;ks<4;ks++) a=__builtin_amdgcn_mfma_f32_16x16x32_f16(Wf[fi][ks],Bf[ks][1],a,0,0,0);
          #pragma unroll
          for(int ks=0;ks<4;ks++) a=__builtin_amdgcn_mfma_f32_16x16x32_f16(Wf[fi][ks],Bf[ks][0],a,0,0,0);
          acc[fi]=a;
        }
        float gv[6][4];
        #pragma unroll
        for(int fi=0;fi<6;fi++){
          gv[fi][0]=h2f((unsigned short)(giB[fi].x&0xffffu));
          gv[fi][1]=h2f((unsigned short)(giB[fi].x>>16));
          gv[fi][2]=h2f((unsigned short)(giB[fi].y&0xffffu));
          gv[fi][3]=h2f((unsigned short)(giB[fi].y>>16));
        }
        if(t+1<T){
          const unsigned short* gpp=GIh+(size_t)sNB*384;
          #pragma unroll
          for(int fi=0;fi<6;fi++){ const int gt=fi>>1, tt=fi&1;
            giB[fi]=*(const uint2*)&gpp[gt*128+32*w+16*tt+4*q]; }
        }
        int ii=t+2; ii=(ii>LB-1)?(LB-1):ii; ii=(ii<0)?0:ii;
        const int sB2=(LB>0)?eB[ii]:0;
        const bool act=(t<LB);
        #pragma unroll
        for(int tt=0;tt<2;tt++)
          #pragma unroll
          for(int r=0;r<4;r++){
            float rr=sigmf(gv[tt][r]+acc[tt][r]);
            float zz=sigmf(gv[2+tt][r]+acc[2+tt][r]);
            float nn=tanh_fast(gv[4+tt][r]+rr*(acc[4+tt][r]+bhn[tt][r]));
            float hn=(1.f-zz)*nn+zz*hB[tt][r];
            hB[tt][r]=act?hn:hB[tt][r];
          }
        #pragma unroll
        for(int tt=0;tt<2;tt++){
          unsigned short a0=f2h(hB[tt][0]),a1=f2h(hB[tt][1]),a2=f2h(hB[tt][2]),a3=f2h(hB[tt][3]);
          unsigned short b0=f2h(hB[tt][0]-h2f(a0)),b1=f2h(hB[tt][1]-h2f(a1));
          unsigned short b2=f2h(hB[tt][2]-h2f(a2)),b3=f2h(hB[tt][3]-h2f(a3));
          const int blk=((4*w+2*tt+(q>>1))^(g&7));
          const int sub=8*(q&1);
          char* p0=(char*)hbuf + (((1*2+cbn)*2+0)*16+g)*256 + blk*16 + sub;
          char* p1=(char*)hbuf + (((1*2+cbn)*2+1)*16+g)*256 + blk*16 + sub;
          *(uint2*)p0=make_uint2((unsigned)a0|((unsigned)a1<<16),(unsigned)a2|((unsigned)a3<<16));
          *(uint2*)p1=make_uint2((unsigned)b0|((unsigned)b1<<16),(unsigned)b2|((unsigned)b3<<16));
        }
        sNB=sB2;
      }
      __syncthreads();
    }
    const int fb=T&1;
    // epilogue A
    #pragma unroll
    for(int tt=0;tt<2;tt++){
      f32x4 a={0.f,0.f,0.f,0.f};
      #pragma unroll
      for(int ks=0;ks<4;ks++){
        const char* ap=(const char*)WnL + (32*w+16*tt+g)*256 + (((4*ks+q)^(g&7))<<4);
        const f16x8 Af=*(const f16x8*)ap;
        const char* bl=(const char*)hbuf + (((0*2+fb)*2+1)*16+g)*256 + (((4*ks+q)^(g&7))<<4);
        const char* bhp=(const char*)hbuf + (((0*2+fb)*2+0)*16+g)*256 + (((4*ks+q)^(g&7))<<4);
        a=__builtin_amdgcn_mfma_f32_16x16x32_f16(Af,*(const f16x8*)bl,a,0,0,0);
        a=__builtin_amdgcn_mfma_f32_16x16x32_f16(Af,*(const f16x8*)bhp,a,0,0,0);
      }
      float* po=&out[(size_t)nA*DIM + 32*w+16*tt+4*q];
      float4 cur=*(float4*)po;
      cur.x+=a[0]; cur.y+=a[1]; cur.z+=a[2]; cur.w+=a[3];
      *(float4*)po=cur;
    }
    // epilogue B
    if(gvB){
      #pragma unroll
      for(int tt=0;tt<2;tt++){
        f32x4 a={0.f,0.f,0.f,0.f};
        #pragma unroll
        for(int ks=0;ks<4;ks++){
          const char* ap=(const char*)WnL + (32*w+16*tt+g)*256 + (((4*ks+q)^(g&7))<<4);
          const f16x8 Af=*(const f16x8*)ap;
          const char* bl=(const char*)hbuf + (((1*2+fb)*2+1)*16+g)*256 + (((4*ks+q)^(g&7))<<4);
          const char* bhp=(const char*)hbuf + (((1*2+fb)*2+0)*16+g)*256 + (((4*ks+q)^(g&7))<<4);
          a=__builtin_amdgcn_mfma_f32_16x16x32_f16(Af,*(const f16x8*)bl,a,0,0,0);
          a=__builtin_amdgcn_mfma_f32_16x16x32_f16(Af,*(const f16x8*)bhp,a,0,0,0);
        }
        float* po=&out[(size_t)nB*DIM + 32*w+16*tt+4*q];
        float4 cur=*(float4*)po;
        cur.x+=a[0]; cur.y+=a[1]; cur.z+=a[2]; cur.w+=a[3];
        *(float4*)po=cur;
      }
    }
  }
}

extern "C" void kernel_launch(void* const* d_in, const int* in_sizes, int n_in,
                              void* d_out, int out_size, void* d_ws, size_t ws_size,
                              hipStream_t stream){
  const float* feat  = (const float*)d_in[0];
  const int*   src   = (const int*)d_in[1];
  const int*   dst   = (const int*)d_in[2];
  const float* gamma = (const float*)d_in[3];
  const float* beta  = (const float*)d_in[4];
  const float* Wih   = (const float*)d_in[5];
  const float* Whh   = (const float*)d_in[6];
  const float* bih   = (const float*)d_in[7];
  const float* bhh   = (const float*)d_in[8];
  const float* Wself = (const float*)d_in[9];
  const float* Wneigh= (const float*)d_in[10];
  float* out = (float*)d_out;

  char* ws = (char*)d_ws;
  size_t off = 0;
  auto alloc = [&](size_t bytes)->void*{ void* p = ws+off; off += (bytes+511)&~(size_t)511; return p; };
  float* P     = (float*)alloc(256*128*4);
  float* P2    = (float*)alloc(256*128*4);
  float* scale = (float*)alloc(512);
  float* shift = (float*)alloc(512);
  int*   cnt   = (int*)alloc((size_t)N_NODES*4);
  int*   lenp  = (int*)alloc((size_t)N_NODES*4);
  int*   hist  = (int*)alloc((MAXD+1)*4);
  int*   offs  = (int*)alloc((MAXD+1)*4);
  int*   perm  = (int*)alloc((size_t)N_NODES*4);
  int*   elist = (int*)alloc((size_t)N_NODES*CAP*4);
  unsigned short* GIh = (unsigned short*)alloc((size_t)N_NODES*384*2);

  kZero2<<<(N_NODES+255)/256, 256, 0, stream>>>(cnt, N_NODES, hist, MAXD+1);
  kColStats<<<256,128,0,stream>>>(feat, P, P2);
  kFinStats<<<1,128,0,stream>>>(P,P2,gamma,beta,scale,shift);
  kEdges<<<1024,256,0,stream>>>(dst, cnt, elist);
  kSortW<<<(N_NODES+3)/4,256,0,stream>>>(src, cnt, elist, lenp, hist);
  kScan<<<1,64,0,stream>>>(hist, offs);
  kScatter<<<(N_NODES+255)/256,256,0,stream>>>(lenp, offs, perm);
  kXG2<<<256,256,0,stream>>>(feat, scale, shift, Wih, bih, bhh, Wself, GIh, out);
  kGruM<<<512,256,0,stream>>>(GIh, elist, lenp, perm, Whh, bhh, Wneigh, out);
}

// Round 6
// 460.322 us; speedup vs baseline: 2.5511x; 1.9130x over previous
//
#include <hip/hip_runtime.h>
#include <hip/hip_fp16.h>

#define N_NODES 50000
#define DIM 128
#define NE 800000
#define MAXD 48
#define CAP 64
#define NGRP (N_NODES/16)
#define NPAIR ((NGRP+1)/2)
#define NBLK ((N_NODES+255)/256)

typedef _Float16 f16x8 __attribute__((ext_vector_type(8)));
typedef float f32x4 __attribute__((ext_vector_type(4)));

__device__ __forceinline__ float sigmf(float x){
  return __builtin_amdgcn_rcpf(1.f + __builtin_amdgcn_exp2f(-1.4426950408889634f * x));
}
__device__ __forceinline__ float tanh_fast(float x){
  float e = __builtin_amdgcn_exp2f(2.8853900817779268f * x);
  return 1.f - 2.f * __builtin_amdgcn_rcpf(e + 1.f);
}
__device__ __forceinline__ unsigned short f2h(float f){
  union{_Float16 h; unsigned short s;} c; c.h=(_Float16)f; return c.s;
}
__device__ __forceinline__ float h2f(unsigned short u){
  union{unsigned short s; _Float16 h;} c; c.s=u; return (float)c.h;
}

__global__ void kZero(int* p, int n){
  int i = blockIdx.x*blockDim.x + threadIdx.x;
  if(i<n) p[i]=0;
}

__global__ void kColStats(const float* __restrict__ feat, float* __restrict__ P, float* __restrict__ P2){
  int d = threadIdx.x; int b = blockIdx.x;
  float s=0.f, s2=0.f;
  for(int r=b; r<N_NODES; r+=256){ float v = feat[r*DIM+d]; s+=v; s2+=v*v; }
  P[b*DIM+d]=s; P2[b*DIM+d]=s2;
}

__global__ void kFinStats(const float* __restrict__ P, const float* __restrict__ P2,
                          const float* __restrict__ gamma, const float* __restrict__ beta,
                          float* __restrict__ scale, float* __restrict__ shift){
  int d = threadIdx.x;
  float s=0.f, s2=0.f;
  for(int b=0;b<256;b++){ s+=P[b*DIM+d]; s2+=P2[b*DIM+d]; }
  float mu = s/(float)N_NODES;
  float var = s2/(float)N_NODES - mu*mu;
  float rs = rsqrtf(var + 1e-5f);
  float sc = rs*gamma[d];
  scale[d]=sc; shift[d]=beta[d]-mu*sc;
}

__global__ void kEdges(const int* __restrict__ dst, int* __restrict__ cnt, int* __restrict__ elist){
  for(int e = blockIdx.x*blockDim.x+threadIdx.x; e < NE; e += gridDim.x*blockDim.x){
    int d = dst[e];
    int slot = atomicAdd(&cnt[d],1);
    if(slot < CAP) elist[(size_t)d*CAP+slot] = e;
  }
}

// One wave per node: 64-lane bitonic sort of edge ids, then resolve to src. No atomics.
__global__ __launch_bounds__(256) void kSortW(const int* __restrict__ src, const int* __restrict__ cnt,
    int* __restrict__ elist, int* __restrict__ len){
  int n = blockIdx.x*4 + (threadIdx.x>>6);
  if(n>=N_NODES) return;
  int l = threadIdx.x&63;
  int m = cnt[n]; m = m>CAP? CAP : m;
  int* el = elist + (size_t)n*CAP;
  int v = (l<m)? el[l] : 0x7fffffff;
  #pragma unroll
  for(int k=2;k<=64;k<<=1){
    #pragma unroll
    for(int j=k>>1;j>0;j>>=1){
      int u = __shfl_xor(v,j);
      bool up = ((l&k)==0);
      bool lower = ((l&j)==0);
      int mn = v<u? v:u, mx = v<u? u:v;
      v = (lower==up)? mn : mx;
    }
  }
  int L = m<MAXD? m : MAXD;
  if(l==0) len[n]=L;
  if(l<L) el[l] = src[v];
}

// Block-aggregated histogram: zero contended global atomics.
__global__ __launch_bounds__(256) void kHistB(const int* __restrict__ len, int* __restrict__ blockHist){
  __shared__ int lh[MAXD+1];
  const int b=blockIdx.x, tid=threadIdx.x;
  if(tid<=MAXD) lh[tid]=0;
  __syncthreads();
  const int n=b*256+tid;
  if(n<N_NODES) atomicAdd(&lh[len[n]],1);
  __syncthreads();
  if(tid<=MAXD) blockHist[tid*NBLK+b]=lh[tid];
}

// Single block: per-bin totals -> exclusive bin bases -> per-(bin,block) bases.
__global__ __launch_bounds__(64) void kScanB(const int* __restrict__ blockHist, int* __restrict__ blockBase){
  __shared__ int tot[MAXD+1];
  __shared__ int base[MAXD+1];
  const int tid=threadIdx.x;
  if(tid<=MAXD){
    int s=0;
    for(int b=0;b<NBLK;b++) s+=blockHist[tid*NBLK+b];
    tot[tid]=s;
  }
  __syncthreads();
  if(tid==0){ int s=0; for(int i=0;i<=MAXD;i++){ base[i]=s; s+=tot[i]; } }
  __syncthreads();
  if(tid<=MAXD){
    int run=base[tid];
    for(int b=0;b<NBLK;b++){ blockBase[tid*NBLK+b]=run; run+=blockHist[tid*NBLK+b]; }
  }
}

// Scatter using LDS-local ranks + precomputed bases (out[] is invariant to within-bin order).
__global__ __launch_bounds__(256) void kScatterB(const int* __restrict__ len,
    const int* __restrict__ blockBase, int* __restrict__ perm){
  __shared__ int lh[MAXD+1];
  const int b=blockIdx.x, tid=threadIdx.x;
  if(tid<=MAXD) lh[tid]=0;
  __syncthreads();
  const int n=b*256+tid;
  if(n<N_NODES){
    int bin=len[n];
    int lr=atomicAdd(&lh[bin],1);
    perm[blockBase[bin*NBLK+b]+lr]=n;
  }
}

// MFMA GEMM: GIh[n][j] = f16(x@Wih^T + bih + (j<256? bhh:0)), out[n] = x@Wself^T.
// BN folded into weights.
__global__ __launch_bounds__(256,1) void kXG2(const float* __restrict__ feat,
    const float* __restrict__ scale, const float* __restrict__ shift,
    const float* __restrict__ Wih, const float* __restrict__ bih, const float* __restrict__ bhh,
    const float* __restrict__ Wself,
    unsigned short* __restrict__ GIh, float* __restrict__ out)
{
  __shared__ unsigned short Wl[512*128];
  __shared__ float bL[512];
  const int tid=threadIdx.x, w=tid>>6, l=tid&63, g=l&15, q=l>>4;
  for(int i=tid;i<8192;i+=256){
    int j=i>>4, blk=i&15, d0=blk*8;
    const float* Wsrc=(j<384)? &Wih[(size_t)j*DIM] : &Wself[(size_t)(j-384)*DIM];
    float partial=0.f; unsigned u[4];
    #pragma unroll
    for(int e2=0;e2<4;e2++){
      float w0=Wsrc[d0+2*e2], w1=Wsrc[d0+2*e2+1];
      partial += shift[d0+2*e2]*w0 + shift[d0+2*e2+1]*w1;
      u[e2]=(unsigned)f2h(w0*scale[d0+2*e2]) | ((unsigned)f2h(w1*scale[d0+2*e2+1])<<16);
    }
    partial+=__shfl_xor(partial,1); partial+=__shfl_xor(partial,2);
    partial+=__shfl_xor(partial,4); partial+=__shfl_xor(partial,8);
    if((i&15)==0){
      float bb=partial;
      if(j<384) bb+=bih[j];
      if(j<256) bb+=bhh[j];
      bL[j]=bb;
    }
    char* dp=(char*)Wl + j*256 + ((blk^(j&7))<<4);
    *(uint4*)dp=make_uint4(u[0],u[1],u[2],u[3]);
  }
  __syncthreads();
  for(int grp=blockIdx.x*4+w; grp<NGRP; grp+=gridDim.x*4){
    const int n=grp*16+g;
    const float* fp=feat+(size_t)n*DIM;
    f16x8 Bf[4];
    #pragma unroll
    for(int ks=0;ks<4;ks++){
      float4 a=*(const float4*)&fp[32*ks+8*q];
      float4 b=*(const float4*)&fp[32*ks+8*q+4];
      f16x8 v; v[0]=(_Float16)a.x; v[1]=(_Float16)a.y; v[2]=(_Float16)a.z; v[3]=(_Float16)a.w;
      v[4]=(_Float16)b.x; v[5]=(_Float16)b.y; v[6]=(_Float16)b.z; v[7]=(_Float16)b.w;
      Bf[ks]=v;
    }
    for(int tile=0;tile<32;tile++){
      const int jbase=tile*16;
      f32x4 a={0.f,0.f,0.f,0.f};
      #pragma unroll
      for(int ks=0;ks<4;ks++){
        const char* ap=(const char*)Wl + (jbase+g)*256 + (((4*ks+q)^(g&7))<<4);
        a=__builtin_amdgcn_mfma_f32_16x16x32_f16(*(const f16x8*)ap,Bf[ks],a,0,0,0);
      }
      float4 bb=*(const float4*)&bL[jbase+4*q];
      if(tile<24){
        unsigned lo=(unsigned)f2h(a[0]+bb.x)|((unsigned)f2h(a[1]+bb.y)<<16);
        unsigned hi=(unsigned)f2h(a[2]+bb.z)|((unsigned)f2h(a[3]+bb.w)<<16);
        *(uint2*)&GIh[(size_t)n*384+jbase+4*q]=make_uint2(lo,hi);
      } else {
        float4 o; o.x=a[0]+bb.x; o.y=a[1]+bb.y; o.z=a[2]+bb.z; o.w=a[3]+bb.w;
        *(float4*)&out[(size_t)n*DIM + (jbase-384)+4*q]=o;
      }
    }
  }
}

// MFMA GRU, two-group software pipeline per 4-wave block.
__global__ __launch_bounds__(256,2) void kGruM(const unsigned short* __restrict__ GIh,
    const int* __restrict__ elist, const int* __restrict__ len, const int* __restrict__ perm,
    const float* __restrict__ Whh, const float* __restrict__ bhh,
    const float* __restrict__ Wneigh, float* __restrict__ out)
{
  __shared__ unsigned short hbuf[2][2][2][16][128]; // [grp][buf][plane][g][d] 32KB, swizzled rows
  __shared__ unsigned short WnL[128*128];           // 32KB swizzled
  const int tid=threadIdx.x, w=tid>>6, l=tid&63, g=l&15, q=l>>4;

  for(int i=tid;i<2048;i+=256){
    int j=i>>4, blk=i&15;
    const float* p=&Wneigh[(size_t)j*DIM + blk*8];
    unsigned u0=(unsigned)f2h(p[0])|((unsigned)f2h(p[1])<<16);
    unsigned u1=(unsigned)f2h(p[2])|((unsigned)f2h(p[3])<<16);
    unsigned u2=(unsigned)f2h(p[4])|((unsigned)f2h(p[5])<<16);
    unsigned u3=(unsigned)f2h(p[6])|((unsigned)f2h(p[7])<<16);
    char* dp=(char*)WnL + j*256 + ((blk^(j&7))<<4);
    *(uint4*)dp=make_uint4(u0,u1,u2,u3);
  }
  f16x8 Wf[6][4];
  #pragma unroll
  for(int fi=0;fi<6;fi++){
    const int gt=fi>>1, tt=fi&1;
    const int j=gt*128+32*w+16*tt+g;
    #pragma unroll
    for(int ks=0;ks<4;ks++){
      const float* p=&Whh[j*DIM+32*ks+8*q];
      f16x8 v;
      #pragma unroll
      for(int e=0;e<8;e++) v[e]=(_Float16)p[e];
      Wf[fi][ks]=v;
    }
  }
  float bhn[2][4];
  #pragma unroll
  for(int tt=0;tt<2;tt++)
    #pragma unroll
    for(int r=0;r<4;r++) bhn[tt][r]=bhh[256+32*w+16*tt+4*q+r];

  for(int gp=blockIdx.x; gp<NPAIR; gp+=gridDim.x){
    __syncthreads();
    for(int i=tid;i<2048;i+=256) ((uint4*)hbuf)[i]=make_uint4(0,0,0,0);
    const int nA=perm[(2*gp)*16+g];
    const bool gvB=(2*gp+1)<NGRP;
    const int nB=gvB? perm[(2*gp+1)*16+g]:0;
    const int LA=len[nA];
    const int LB=gvB? len[nB]:0;
    int T=LA>LB?LA:LB;
    T=max(T,__shfl_xor(T,1)); T=max(T,__shfl_xor(T,2));
    T=max(T,__shfl_xor(T,4)); T=max(T,__shfl_xor(T,8));
    __syncthreads();
    if(T==0) continue;
    const int* eA=elist+(size_t)nA*CAP;
    const int* eB=elist+(size_t)nB*CAP;
    int sNA, sNB;
    uint2 giA[6], giB[6];
    {
      int s0=(LA>0)?eA[0]:0;
      sNA=(LA>1)?eA[1]:s0;
      const unsigned short* gpp=GIh+(size_t)s0*384;
      #pragma unroll
      for(int fi=0;fi<6;fi++){ const int gt=fi>>1, tt=fi&1;
        giA[fi]=*(const uint2*)&gpp[gt*128+32*w+16*tt+4*q]; }
      int s0b=(LB>0)?eB[0]:0;
      sNB=(LB>1)?eB[1]:s0b;
      const unsigned short* gpb=GIh+(size_t)s0b*384;
      #pragma unroll
      for(int fi=0;fi<6;fi++){ const int gt=fi>>1, tt=fi&1;
        giB[fi]=*(const uint2*)&gpb[gt*128+32*w+16*tt+4*q]; }
    }
    float hA[2][4]={{0.f,0.f,0.f,0.f},{0.f,0.f,0.f,0.f}};
    float hB[2][4]={{0.f,0.f,0.f,0.f},{0.f,0.f,0.f,0.f}};
    for(int t=0;t<T;t++){
      const int cb=t&1, cbn=cb^1;
      // ================= group A =================
      {
        f16x8 Bf[4][2];
        #pragma unroll
        for(int ks=0;ks<4;ks++)
          #pragma unroll
          for(int p=0;p<2;p++){
            const char* bp=(const char*)hbuf + (((0*2+cb)*2+p)*16+g)*256 + (((4*ks+q)^(g&7))<<4);
            Bf[ks][p]=*(const f16x8*)bp;
          }
        f32x4 acc[6];
        #pragma unroll
        for(int fi=0;fi<6;fi++){
          f32x4 a={0.f,0.f,0.f,0.f};
          #pragma unroll
          for(int ks=0;ks<4;ks++) a=__builtin_amdgcn_mfma_f32_16x16x32_f16(Wf[fi][ks],Bf[ks][1],a,0,0,0);
          #pragma unroll
          for(int ks=0;ks<4;ks++) a=__builtin_amdgcn_mfma_f32_16x16x32_f16(Wf[fi][ks],Bf[ks][0],a,0,0,0);
          acc[fi]=a;
        }
        float gv[6][4];
        #pragma unroll
        for(int fi=0;fi<6;fi++){
          gv[fi][0]=h2f((unsigned short)(giA[fi].x&0xffffu));
          gv[fi][1]=h2f((unsigned short)(giA[fi].x>>16));
          gv[fi][2]=h2f((unsigned short)(giA[fi].y&0xffffu));
          gv[fi][3]=h2f((unsigned short)(giA[fi].y>>16));
        }
        if(t+1<T){
          const unsigned short* gpp=GIh+(size_t)sNA*384;
          #pragma unroll
          for(int fi=0;fi<6;fi++){ const int gt=fi>>1, tt=fi&1;
            giA[fi]=*(const uint2*)&gpp[gt*128+32*w+16*tt+4*q]; }
        }
        int ii=t+2; ii=(ii>LA-1)?(LA-1):ii; ii=(ii<0)?0:ii;
        const int sA2=(LA>0)?eA[ii]:0;
        const bool act=(t<LA);
        #pragma unroll
        for(int tt=0;tt<2;tt++)
          #pragma unroll
          for(int r=0;r<4;r++){
            float rr=sigmf(gv[tt][r]+acc[tt][r]);
            float zz=sigmf(gv[2+tt][r]+acc[2+tt][r]);
            float nn=tanh_fast(gv[4+tt][r]+rr*(acc[4+tt][r]+bhn[tt][r]));
            float hn=(1.f-zz)*nn+zz*hA[tt][r];
            hA[tt][r]=act?hn:hA[tt][r];
          }
        #pragma unroll
        for(int tt=0;tt<2;tt++){
          unsigned short a0=f2h(hA[tt][0]),a1=f2h(hA[tt][1]),a2=f2h(hA[tt][2]),a3=f2h(hA[tt][3]);
          unsigned short b0=f2h(hA[tt][0]-h2f(a0)),b1=f2h(hA[tt][1]-h2f(a1));
          unsigned short b2=f2h(hA[tt][2]-h2f(a2)),b3=f2h(hA[tt][3]-h2f(a3));
          const int blk=((4*w+2*tt+(q>>1))^(g&7));
          const int sub=8*(q&1);
          char* p0=(char*)hbuf + (((0*2+cbn)*2+0)*16+g)*256 + blk*16 + sub;
          char* p1=(char*)hbuf + (((0*2+cbn)*2+1)*16+g)*256 + blk*16 + sub;
          *(uint2*)p0=make_uint2((unsigned)a0|((unsigned)a1<<16),(unsigned)a2|((unsigned)a3<<16));
          *(uint2*)p1=make_uint2((unsigned)b0|((unsigned)b1<<16),(unsigned)b2|((unsigned)b3<<16));
        }
        sNA=sA2;
      }
      // ================= group B =================
      {
        f16x8 Bf[4][2];
        #pragma unroll
        for(int ks=0;ks<4;ks++)
          #pragma unroll
          for(int p=0;p<2;p++){
            const char* bp=(const char*)hbuf + (((1*2+cb)*2+p)*16+g)*256 + (((4*ks+q)^(g&7))<<4);
            Bf[ks][p]=*(const f16x8*)bp;
          }
        f32x4 acc[6];
        #pragma unroll
        for(int fi=0;fi<6;fi++){
          f32x4 a={0.f,0.f,0.f,0.f};
          #pragma unroll
          for(int ks=0;ks<4;ks++) a=__builtin_amdgcn_mfma_f32_16x16x32_f16(Wf[fi][ks],Bf[ks][1],a,0,0,0);
          #pragma unroll
          for(int ks=0;ks<4;ks++) a=__builtin_amdgcn_mfma_f32_16x16x32_f16(Wf[fi][ks],Bf[ks][0],a,0,0,0);
          acc[fi]=a;
        }
        float gv[6][4];
        #pragma unroll
        for(int fi=0;fi<6;fi++){
          gv[fi][0]=h2f((unsigned short)(giB[fi].x&0xffffu));
          gv[fi][1]=h2f((unsigned short)(giB[fi].x>>16));
          gv[fi][2]=h2f((unsigned short)(giB[fi].y&0xffffu));
          gv[fi][3]=h2f((unsigned short)(giB[fi].y>>16));
        }
        if(t+1<T){
          const unsigned short* gpp=GIh+(size_t)sNB*384;
          #pragma unroll
          for(int fi=0;fi<6;fi++){ const int gt=fi>>1, tt=fi&1;
            giB[fi]=*(const uint2*)&gpp[gt*128+32*w+16*tt+4*q]; }
        }
        int ii=t+2; ii=(ii>LB-1)?(LB-1):ii; ii=(ii<0)?0:ii;
        const int sB2=(LB>0)?eB[ii]:0;
        const bool act=(t<LB);
        #pragma unroll
        for(int tt=0;tt<2;tt++)
          #pragma unroll
          for(int r=0;r<4;r++){
            float rr=sigmf(gv[tt][r]+acc[tt][r]);
            float zz=sigmf(gv[2+tt][r]+acc[2+tt][r]);
            float nn=tanh_fast(gv[4+tt][r]+rr*(acc[4+tt][r]+bhn[tt][r]));
            float hn=(1.f-zz)*nn+zz*hB[tt][r];
            hB[tt][r]=act?hn:hB[tt][r];
          }
        #pragma unroll
        for(int tt=0;tt<2;tt++){
          unsigned short a0=f2h(hB[tt][0]),a1=f2h(hB[tt][1]),a2=f2h(hB[tt][2]),a3=f2h(hB[tt][3]);
          unsigned short b0=f2h(hB[tt][0]-h2f(a0)),b1=f2h(hB[tt][1]-h2f(a1));
          unsigned short b2=f2h(hB[tt][2]-h2f(a2)),b3=f2h(hB[tt][3]-h2f(a3));
          const int blk=((4*w+2*tt+(q>>1))^(g&7));
          const int sub=8*(q&1);
          char* p0=(char*)hbuf + (((1*2+cbn)*2+0)*16+g)*256 + blk*16 + sub;
          char* p1=(char*)hbuf + (((1*2+cbn)*2+1)*16+g)*256 + blk*16 + sub;
          *(uint2*)p0=make_uint2((unsigned)a0|((unsigned)a1<<16),(unsigned)a2|((unsigned)a3<<16));
          *(uint2*)p1=make_uint2((unsigned)b0|((unsigned)b1<<16),(unsigned)b2|((unsigned)b3<<16));
        }
        sNB=sB2;
      }
      __syncthreads();
    }
    const int fb=T&1;
    // epilogue A
    #pragma unroll
    for(int tt=0;tt<2;tt++){
      f32x4 a={0.f,0.f,0.f,0.f};
      #pragma unroll
      for(int ks=0;ks<4;ks++){
        const char* ap=(const char*)WnL + (32*w+16*tt+g)*256 + (((4*ks+q)^(g&7))<<4);
        const f16x8 Af=*(const f16x8*)ap;
        const char* bl=(const char*)hbuf + (((0*2+fb)*2+1)*16+g)*256 + (((4*ks+q)^(g&7))<<4);
        const char* bhp=(const char*)hbuf + (((0*2+fb)*2+0)*16+g)*256 + (((4*ks+q)^(g&7))<<4);
        a=__builtin_amdgcn_mfma_f32_16x16x32_f16(Af,*(const f16x8*)bl,a,0,0,0);
        a=__builtin_amdgcn_mfma_f32_16x16x32_f16(Af,*(const f16x8*)bhp,a,0,0,0);
      }
      float* po=&out[(size_t)nA*DIM + 32*w+16*tt+4*q];
      float4 cur=*(float4*)po;
      cur.x+=a[0]; cur.y+=a[1]; cur.z+=a[2]; cur.w+=a[3];
      *(float4*)po=cur;
    }
    // epilogue B
    if(gvB){
      #pragma unroll
      for(int tt=0;tt<2;tt++){
        f32x4 a={0.f,0.f,0.f,0.f};
        #pragma unroll
        for(int ks=0;ks<4;ks++){
          const char* ap=(const char*)WnL + (32*w+16*tt+g)*256 + (((4*ks+q)^(g&7))<<4);
          const f16x8 Af=*(const f16x8*)ap;
          const char* bl=(const char*)hbuf + (((1*2+fb)*2+1)*16+g)*256 + (((4*ks+q)^(g&7))<<4);
          const char* bhp=(const char*)hbuf + (((1*2+fb)*2+0)*16+g)*256 + (((4*ks+q)^(g&7))<<4);
          a=__builtin_amdgcn_mfma_f32_16x16x32_f16(Af,*(const f16x8*)bl,a,0,0,0);
          a=__builtin_amdgcn_mfma_f32_16x16x32_f16(Af,*(const f16x8*)bhp,a,0,0,0);
        }
        float* po=&out[(size_t)nB*DIM + 32*w+16*tt+4*q];
        float4 cur=*(float4*)po;
        cur.x+=a[0]; cur.y+=a[1]; cur.z+=a[2]; cur.w+=a[3];
        *(float4*)po=cur;
      }
    }
  }
}

extern "C" void kernel_launch(void* const* d_in, const int* in_sizes, int n_in,
                              void* d_out, int out_size, void* d_ws, size_t ws_size,
                              hipStream_t stream){
  const float* feat  = (const float*)d_in[0];
  const int*   src   = (const int*)d_in[1];
  const int*   dst   = (const int*)d_in[2];
  const float* gamma = (const float*)d_in[3];
  const float* beta  = (const float*)d_in[4];
  const float* Wih   = (const float*)d_in[5];
  const float* Whh   = (const float*)d_in[6];
  const float* bih   = (const float*)d_in[7];
  const float* bhh   = (const float*)d_in[8];
  const float* Wself = (const float*)d_in[9];
  const float* Wneigh= (const float*)d_in[10];
  float* out = (float*)d_out;

  char* ws = (char*)d_ws;
  size_t off = 0;
  auto alloc = [&](size_t bytes)->void*{ void* p = ws+off; off += (bytes+511)&~(size_t)511; return p; };
  float* P     = (float*)alloc(256*128*4);
  float* P2    = (float*)alloc(256*128*4);
  float* scale = (float*)alloc(512);
  float* shift = (float*)alloc(512);
  int*   cnt   = (int*)alloc((size_t)N_NODES*4);
  int*   lenp  = (int*)alloc((size_t)N_NODES*4);
  int*   blockHist = (int*)alloc((size_t)(MAXD+1)*NBLK*4);
  int*   blockBase = (int*)alloc((size_t)(MAXD+1)*NBLK*4);
  int*   perm  = (int*)alloc((size_t)N_NODES*4);
  int*   elist = (int*)alloc((size_t)N_NODES*CAP*4);
  unsigned short* GIh = (unsigned short*)alloc((size_t)N_NODES*384*2);

  kZero<<<(N_NODES+255)/256, 256, 0, stream>>>(cnt, N_NODES);
  kColStats<<<256,128,0,stream>>>(feat, P, P2);
  kFinStats<<<1,128,0,stream>>>(P,P2,gamma,beta,scale,shift);
  kEdges<<<1024,256,0,stream>>>(dst, cnt, elist);
  kSortW<<<(N_NODES+3)/4,256,0,stream>>>(src, cnt, elist, lenp);
  kHistB<<<NBLK,256,0,stream>>>(lenp, blockHist);
  kScanB<<<1,64,0,stream>>>(blockHist, blockBase);
  kScatterB<<<NBLK,256,0,stream>>>(lenp, blockBase, perm);
  kXG2<<<256,256,0,stream>>>(feat, scale, shift, Wih, bih, bhh, Wself, GIh, out);
  kGruM<<<512,256,0,stream>>>(GIh, elist, lenp, perm, Whh, bhh, Wneigh, out);
}